// Round 4
// baseline (245.727 us; speedup 1.0000x reference)
//
#include <hip/hip_runtime.h>
#include <hip/hip_bf16.h>

// ---------------------------------------------------------------------------
// OrthoInitPhasor round 4
//   prep_all:     cvt x->bf16, pack Wv/Wo, cvt Wkm/Wqm, transpose Wk/Wq,
//                 compose biases                     (one kernel)
//   gemm_compose: Wkk = Wkm@Wk, Wqq = Wqm@Wq via MFMA
//   GEMM_A:       x @ [Wv|Wkk|Wqq]^T + bias -> VKQ interleaved [t][512][4]
//   fused_pg:     phasor+cumsum+LN (LDS) + MFMA GEMM vs Wo + resid -> out
// ---------------------------------------------------------------------------

typedef __attribute__((ext_vector_type(8))) short short8;   // 8 x bf16
typedef __attribute__((ext_vector_type(4))) float f32x4;

#define M_TOK   16384
#define DIM     512
#define NCHUNK  64
#define RPAD    520   // LDS row stride (bf16 elems) for normed tile

__device__ __forceinline__ void gll16(const void* g, void* l) {
  __builtin_amdgcn_global_load_lds(
      (const __attribute__((address_space(1))) unsigned int*)g,
      (__attribute__((address_space(3))) unsigned int*)l, 16, 0, 0);
}

__device__ __forceinline__ uint2 pack4bf(float4 v) {
  union { __hip_bfloat16 h[4]; uint2 u; } t;
  t.h[0] = __float2bfloat16(v.x);
  t.h[1] = __float2bfloat16(v.y);
  t.h[2] = __float2bfloat16(v.z);
  t.h[3] = __float2bfloat16(v.w);
  return t.u;
}

// ------------------------------ prep (merged) ------------------------------
// blocks 0..8191        : cvt x -> x_bf (float4 per thread)
// +0..511   (8192..)    : pack Wv -> Wall[0:512), Wo -> Wall[1536:2048); bv
// +512..1023            : cvt Wkm/Wqm -> Wm_bf
// +1024..1151           : transpose-cvt Wk/Wq -> WT_bf (64x64 tiles)
// +1152..1407           : compose biases (wave per row)
__global__ __launch_bounds__(256) void prep_all(
    const float* __restrict__ x, __hip_bfloat16* __restrict__ x_bf,
    const float* __restrict__ Wv, const float* __restrict__ Wo,
    const float* __restrict__ bv,
    const float* __restrict__ Wkm, const float* __restrict__ Wqm,
    const float* __restrict__ Wk, const float* __restrict__ Wq,
    const float* __restrict__ bk, const float* __restrict__ bkm,
    const float* __restrict__ bq, const float* __restrict__ bqm,
    __hip_bfloat16* __restrict__ Wall, float* __restrict__ bc1,
    __hip_bfloat16* __restrict__ Wm_bf, __hip_bfloat16* __restrict__ WT_bf) {
  const int tid = threadIdx.x;
  if (blockIdx.x < 8192) {
    int i = blockIdx.x * 256 + tid;          // 2097152 float4s
    ((uint2*)x_bf)[i] = pack4bf(((const float4*)x)[i]);
    return;
  }
  const int b = blockIdx.x - 8192;
  if (b < 512) {
    int m = b >> 8;
    int idx = ((b & 255) * 256 + tid) * 4;
    const float* src = m ? Wo : Wv;
    __hip_bfloat16* dst = Wall + (m ? (size_t)1536 * 512 : 0);
    ((uint2*)dst)[idx >> 2] = pack4bf(*(const float4*)(src + idx));
    int t = b * 256 + tid;
    if (t < 512) bc1[t] = bv[t];
  } else if (b < 1024) {
    int bb = b - 512;
    int m = bb >> 8;
    int idx = ((bb & 255) * 256 + tid) * 4;
    const float* src = m ? Wqm : Wkm;
    ((uint2*)(Wm_bf + (size_t)m * 262144))[idx >> 2] =
        pack4bf(*(const float4*)(src + idx));
  } else if (b < 1152) {
    __shared__ float tile[64][65];
    int bb = b - 1024;
    int z = bb >> 6;
    int tl = bb & 63;
    int tr = tl >> 3, tc = tl & 7;
    const float* src = z ? Wq : Wk;
#pragma unroll
    for (int i = 0; i < 4; i++) {
      int r = (tid >> 4) + 16 * i;
      int c4 = (tid & 15) * 4;
      float4 v = *(const float4*)(src + (size_t)(tr * 64 + r) * 512 +
                                  tc * 64 + c4);
      tile[r][c4 + 0] = v.x;
      tile[r][c4 + 1] = v.y;
      tile[r][c4 + 2] = v.z;
      tile[r][c4 + 3] = v.w;
    }
    __syncthreads();
    int orow = tid >> 2;
    int seg = tid & 3;
    __hip_bfloat16* dst = WT_bf + (size_t)z * 262144 +
                          (size_t)(tc * 64 + orow) * 512 + tr * 64 + seg * 16;
#pragma unroll
    for (int q = 0; q < 4; q++) {
      float4 v;
      v.x = tile[seg * 16 + q * 4 + 0][orow];
      v.y = tile[seg * 16 + q * 4 + 1][orow];
      v.z = tile[seg * 16 + q * 4 + 2][orow];
      v.w = tile[seg * 16 + q * 4 + 3][orow];
      *(uint2*)(dst + q * 4) = pack4bf(v);
    }
  } else {
    int row = (b - 1152) * 4 + (tid >> 6);
    int lane = tid & 63;
    int z = row >> 9;
    int i = row & 511;
    const float* Wm = z ? Wqm : Wkm;
    const float* b0 = z ? bq : bk;
    const float* bm = z ? bqm : bkm;
    const float4* w4 = (const float4*)(Wm + (size_t)i * 512 + lane * 8);
    const float4* v4 = (const float4*)(b0 + lane * 8);
    float4 w0 = w4[0], w1 = w4[1], c0 = v4[0], c1 = v4[1];
    float acc = w0.x * c0.x + w0.y * c0.y + w0.z * c0.z + w0.w * c0.w +
                w1.x * c1.x + w1.y * c1.y + w1.z * c1.z + w1.w * c1.w;
#pragma unroll
    for (int off = 32; off; off >>= 1) acc += __shfl_xor(acc, off, 64);
    if (lane == 0) bc1[512 + z * 512 + i] = acc + bm[i];
  }
}

// ------------------------------- GEMM (B^T) --------------------------------
// EPI 0: bf16 to Cout (ldc)   EPI 2: bf16 interleaved [t][512][4] slot=col>>9
template <int EPI>
__global__ __launch_bounds__(256) void gemm_bt(
    const __hip_bfloat16* __restrict__ A, int lda,
    const __hip_bfloat16* __restrict__ Bt,
    const float* __restrict__ bias,
    void* __restrict__ Cout, int ldc) {
  constexpr int K = 512, BK = 32;
  __shared__ __align__(16) __hip_bfloat16 As[128 * BK];
  __shared__ __align__(16) __hip_bfloat16 Bs[128 * BK];

  const int tid  = threadIdx.x;
  const int lane = tid & 63;
  const int w    = tid >> 6;
  const int wm   = w >> 1;
  const int wn   = w & 1;
  const int m0   = blockIdx.y * 128;
  const int n0   = blockIdx.x * 128;

  const int rS0    = (w * 2 + 0) * 16 + (lane >> 2);
  const int rS1    = (w * 2 + 1) * 16 + (lane >> 2);
  const int kInRow = (lane & 3) * 8;
  const __hip_bfloat16* gA0 = A + (size_t)(m0 + rS0) * lda + kInRow;
  const __hip_bfloat16* gA1 = A + (size_t)(m0 + rS1) * lda + kInRow;
  const __hip_bfloat16* gB0 = Bt + (size_t)(n0 + rS0) * K + kInRow;
  const __hip_bfloat16* gB1 = Bt + (size_t)(n0 + rS1) * K + kInRow;
  char* ldsA0 = (char*)As + (w * 2 + 0) * 1024;
  char* ldsA1 = (char*)As + (w * 2 + 1) * 1024;
  char* ldsB0 = (char*)Bs + (w * 2 + 0) * 1024;
  char* ldsB1 = (char*)Bs + (w * 2 + 1) * 1024;

  f32x4 acc[4][4] = {};

  const int rfA = lane & 15;
  const int rfK = (lane >> 4) * 8;

  for (int kt = 0; kt < K; kt += BK) {
    __syncthreads();
    gll16(gA0 + kt, ldsA0);
    gll16(gA1 + kt, ldsA1);
    gll16(gB0 + kt, ldsB0);
    gll16(gB1 + kt, ldsB1);
    __syncthreads();

    short8 af[4], bf[4];
#pragma unroll
    for (int i = 0; i < 4; i++)
      af[i] = *(const short8*)(As + (wm * 64 + i * 16 + rfA) * BK + rfK);
#pragma unroll
    for (int j = 0; j < 4; j++)
      bf[j] = *(const short8*)(Bs + (wn * 64 + j * 16 + rfA) * BK + rfK);
#pragma unroll
    for (int i = 0; i < 4; i++)
#pragma unroll
      for (int j = 0; j < 4; j++)
        acc[i][j] = __builtin_amdgcn_mfma_f32_16x16x32_bf16(
            af[i], bf[j], acc[i][j], 0, 0, 0);
  }

  const int cq = lane >> 4;
#pragma unroll
  for (int i = 0; i < 4; i++) {
    int row = m0 + wm * 64 + i * 16 + cq * 4;
#pragma unroll
    for (int j = 0; j < 4; j++) {
      int col = n0 + wn * 64 + j * 16 + (lane & 15);
      float bz = bias[col];
#pragma unroll
      for (int r = 0; r < 4; r++) {
        float v = acc[i][j][r] + bz;
        if (EPI == 0) {
          ((__hip_bfloat16*)Cout)[(size_t)(row + r) * ldc + col] =
              __float2bfloat16(v);
        } else {
          size_t o = (size_t)(row + r) * 2048 + (col & 511) * 4 + (col >> 9);
          ((__hip_bfloat16*)Cout)[o] = __float2bfloat16(v);
        }
      }
    }
  }
}

// --------------- compose GEMM: Wkk=Wkm@Wk, Wqq=Wqm@Wq (MFMA) ---------------
__global__ __launch_bounds__(256) void gemm_compose(
    const __hip_bfloat16* __restrict__ Wm_bf,
    const __hip_bfloat16* __restrict__ WT_bf,
    __hip_bfloat16* __restrict__ Wall) {
  constexpr int K = 512, BK = 32;
  const __hip_bfloat16* A  = Wm_bf + (size_t)blockIdx.z * 262144;
  const __hip_bfloat16* Bt = WT_bf + (size_t)blockIdx.z * 262144;
  __hip_bfloat16* C = Wall + (size_t)(512 + blockIdx.z * 512) * 512;
  __shared__ __align__(16) __hip_bfloat16 As[128 * BK];
  __shared__ __align__(16) __hip_bfloat16 Bs[128 * BK];

  const int tid  = threadIdx.x;
  const int lane = tid & 63;
  const int w    = tid >> 6;
  const int wm   = w >> 1;
  const int wn   = w & 1;
  const int m0   = blockIdx.y * 128;
  const int n0   = blockIdx.x * 128;

  const int rS0    = (w * 2 + 0) * 16 + (lane >> 2);
  const int rS1    = (w * 2 + 1) * 16 + (lane >> 2);
  const int kInRow = (lane & 3) * 8;
  const __hip_bfloat16* gA0 = A + (size_t)(m0 + rS0) * K + kInRow;
  const __hip_bfloat16* gA1 = A + (size_t)(m0 + rS1) * K + kInRow;
  const __hip_bfloat16* gB0 = Bt + (size_t)(n0 + rS0) * K + kInRow;
  const __hip_bfloat16* gB1 = Bt + (size_t)(n0 + rS1) * K + kInRow;
  char* ldsA0 = (char*)As + (w * 2 + 0) * 1024;
  char* ldsA1 = (char*)As + (w * 2 + 1) * 1024;
  char* ldsB0 = (char*)Bs + (w * 2 + 0) * 1024;
  char* ldsB1 = (char*)Bs + (w * 2 + 1) * 1024;

  f32x4 acc[4][4] = {};
  const int rfA = lane & 15;
  const int rfK = (lane >> 4) * 8;

  for (int kt = 0; kt < K; kt += BK) {
    __syncthreads();
    gll16(gA0 + kt, ldsA0);
    gll16(gA1 + kt, ldsA1);
    gll16(gB0 + kt, ldsB0);
    gll16(gB1 + kt, ldsB1);
    __syncthreads();

    short8 af[4], bf[4];
#pragma unroll
    for (int i = 0; i < 4; i++)
      af[i] = *(const short8*)(As + (wm * 64 + i * 16 + rfA) * BK + rfK);
#pragma unroll
    for (int j = 0; j < 4; j++)
      bf[j] = *(const short8*)(Bs + (wn * 64 + j * 16 + rfA) * BK + rfK);
#pragma unroll
    for (int i = 0; i < 4; i++)
#pragma unroll
      for (int j = 0; j < 4; j++)
        acc[i][j] = __builtin_amdgcn_mfma_f32_16x16x32_bf16(
            af[i], bf[j], acc[i][j], 0, 0, 0);
  }

  const int cq = lane >> 4;
#pragma unroll
  for (int i = 0; i < 4; i++) {
    int row = m0 + wm * 64 + i * 16 + cq * 4;
#pragma unroll
    for (int j = 0; j < 4; j++) {
      int col = n0 + wn * 64 + j * 16 + (lane & 15);
#pragma unroll
      for (int r = 0; r < 4; r++)
        C[(size_t)(row + r) * 512 + col] = __float2bfloat16(acc[i][j][r]);
    }
  }
}

// ------ fused: phasor + chunk cumsum + LayerNorm + GEMM(Wo) + resid --------
// grid 256 (= B*nC), 512 threads (8 waves). One chunk (64 tokens) per block.
// Phase 1: thread per column d; serial cumsum over 64 tokens; normed tile
//          kept in LDS R[64][RPAD] (bf16).
// Phase 2: barrier-free MFMA K-loop: A-frags from LDS, B-frags (Wo, L2-
//          resident) direct from global. Epilogue: + bo + x -> out (f32).
__global__ __launch_bounds__(512) void fused_pg(
    const __hip_bfloat16* __restrict__ VKQ,   // [16384][512][4] interleaved
    const float* __restrict__ bp,             // [4096,512]
    const float* __restrict__ mod_scale,
    const float* __restrict__ ln_g, const float* __restrict__ ln_b,
    const __hip_bfloat16* __restrict__ WoB,   // [512,512] bf16 (= Wall+1536*512)
    const float* __restrict__ bo,
    const float* __restrict__ x,              // resid f32
    float* __restrict__ out) {
  __shared__ __hip_bfloat16 R[64 * RPAD];     // 66.5 KB
  const int tid    = threadIdx.x;
  const int blk    = blockIdx.x;
  const int token0 = blk * 64;
  const int sg0    = (blk & (NCHUNK - 1)) * 64;
  const float msc  = mod_scale[0];
  const float inv_sqrt_d = 0.044194173824159216f;

  // ---- phase 1: phasor + cumsum ----
  {
    const int d = tid;                        // 0..511
    float mr = 0.f, mi = 0.f;
    const __hip_bfloat16* vb = VKQ + (size_t)token0 * 2048 + d * 4;
    const float* bb = bp + (size_t)sg0 * 512 + d;
#pragma unroll 4
    for (int s = 0; s < 64; ++s) {
      union { uint2 u; __hip_bfloat16 h[4]; } p;
      p.u = *(const uint2*)(vb + (size_t)s * 2048);
      float b  = bb[(size_t)s * 512];
      float v  = __bfloat162float(p.h[0]);
      float km = __bfloat162float(p.h[1]);
      float qm = __bfloat162float(p.h[2]);
      float kp = b + km * msc;
      float qp = b + qm * msc;
      float sk, ck, sq, cq;
      __sincosf(kp, &sk, &ck);
      __sincosf(qp, &sq, &cq);
      mr += v * ck;
      mi += v * sk;
      R[s * RPAD + d] = __float2bfloat16((mr * cq + mi * sq) * inv_sqrt_d);
    }
  }
  __syncthreads();

  // ---- phase 1.5: LayerNorm in place (wave wv owns rows wv*8..+7) ----
  {
    const int lane = tid & 63;
    const int wv   = tid >> 6;
    float gj[8], bj[8];
#pragma unroll
    for (int j = 0; j < 8; j++) {
      int col = lane + 64 * j;
      gj[j] = ln_g[col];
      bj[j] = ln_b[col];
    }
    for (int rr = 0; rr < 8; ++rr) {
      int row = wv * 8 + rr;
      float vals[8], sum = 0.f, sq2 = 0.f;
#pragma unroll
      for (int j = 0; j < 8; j++) {
        float v = __bfloat162float(R[row * RPAD + lane + 64 * j]);
        vals[j] = v;
        sum += v;
        sq2 += v * v;
      }
#pragma unroll
      for (int off = 32; off; off >>= 1) {
        sum += __shfl_xor(sum, off, 64);
        sq2 += __shfl_xor(sq2, off, 64);
      }
      float mu   = sum * (1.f / 512.f);
      float var  = sq2 * (1.f / 512.f) - mu * mu;
      float rstd = rsqrtf(var + 1e-5f);
#pragma unroll
      for (int j = 0; j < 8; j++) {
        float nv = (vals[j] - mu) * rstd * gj[j] + bj[j];
        R[row * RPAD + lane + 64 * j] = __float2bfloat16(nv);
      }
    }
  }
  __syncthreads();

  // ---- phase 2: C(64x512) = R(64x512) @ WoB^T + bo + x -> out ----
  {
    const int lane = tid & 63;
    const int w    = tid >> 6;                // wave 0..7 -> cols w*64..+63
    const int rfA  = lane & 15;
    const int rfK  = (lane >> 4) * 8;
    f32x4 acc[4][4] = {};                     // [row-tile i][col-tile j]

    for (int kt = 0; kt < 512; kt += 32) {
      short8 af[4], bf[4];
#pragma unroll
      for (int j = 0; j < 4; j++) {
        int col = w * 64 + j * 16 + rfA;
        bf[j] = *(const short8*)(WoB + (size_t)col * 512 + kt + rfK);
      }
#pragma unroll
      for (int i = 0; i < 4; i++)
        af[i] = *(const short8*)(R + (i * 16 + rfA) * RPAD + kt + rfK);
#pragma unroll
      for (int i = 0; i < 4; i++)
#pragma unroll
        for (int j = 0; j < 4; j++)
          acc[i][j] = __builtin_amdgcn_mfma_f32_16x16x32_bf16(
              af[i], bf[j], acc[i][j], 0, 0, 0);
    }

    const int cq = lane >> 4;
    float bz[4];
#pragma unroll
    for (int j = 0; j < 4; j++) bz[j] = bo[w * 64 + j * 16 + (lane & 15)];
#pragma unroll
    for (int i = 0; i < 4; i++) {
      int row = token0 + i * 16 + cq * 4;
#pragma unroll
      for (int j = 0; j < 4; j++) {
        int col = w * 64 + j * 16 + (lane & 15);
#pragma unroll
        for (int r = 0; r < 4; r++) {
          size_t o = (size_t)(row + r) * 512 + col;
          out[o] = acc[i][j][r] + bz[j] + x[o];
        }
      }
    }
  }
}

// ------------------------------- launcher ----------------------------------
extern "C" void kernel_launch(void* const* d_in, const int* in_sizes, int n_in,
                              void* d_out, int out_size, void* d_ws,
                              size_t ws_size, hipStream_t stream) {
  const float* x    = (const float*)d_in[0];
  const float* bp   = (const float*)d_in[1];
  const float* Wk   = (const float*)d_in[2];
  const float* bk   = (const float*)d_in[3];
  const float* Wv   = (const float*)d_in[4];
  const float* bv   = (const float*)d_in[5];
  const float* Wq   = (const float*)d_in[6];
  const float* bq   = (const float*)d_in[7];
  const float* Wkm  = (const float*)d_in[8];
  const float* bkm  = (const float*)d_in[9];
  const float* Wqm  = (const float*)d_in[10];
  const float* bqm  = (const float*)d_in[11];
  const float* msc  = (const float*)d_in[12];
  const float* lng  = (const float*)d_in[13];
  const float* lnb  = (const float*)d_in[14];
  const float* Wo   = (const float*)d_in[15];
  const float* bo   = (const float*)d_in[16];
  float* out = (float*)d_out;

  char* ws = (char*)d_ws;
  __hip_bfloat16* x_bf  = (__hip_bfloat16*)ws;  ws += (size_t)M_TOK * DIM * 2;
  __hip_bfloat16* Wall  = (__hip_bfloat16*)ws;  ws += (size_t)2048 * 512 * 2;
  __hip_bfloat16* Wm_bf = (__hip_bfloat16*)ws;  ws += (size_t)2 * 262144 * 2;
  __hip_bfloat16* WT_bf = (__hip_bfloat16*)ws;  ws += (size_t)2 * 262144 * 2;
  float*          bc1   = (float*)ws;           ws += 1536 * 4;
  __hip_bfloat16* VKQ   = (__hip_bfloat16*)ws;  ws += (size_t)M_TOK * 2048 * 2;

  // 1) merged prep: cvt x + pack/cvt/transpose weights + compose biases
  prep_all<<<9600, 256, 0, stream>>>(x, x_bf, Wv, Wo, bv, Wkm, Wqm, Wk, Wq,
                                     bk, bkm, bq, bqm, Wall, bc1, Wm_bf,
                                     WT_bf);
  // 2) MFMA compose: Wkk, Wqq -> Wall rows 512..1535
  gemm_compose<<<dim3(4, 4, 2), 256, 0, stream>>>(Wm_bf, WT_bf, Wall);
  // 3) VKQ = x @ [Wv|Wkk|Wqq]^T + bias, interleaved [t][512][4]
  gemm_bt<2><<<dim3(12, 128), 256, 0, stream>>>(x_bf, DIM, Wall, bc1, VKQ,
                                                2048);
  // 4) fused phasor + cumsum + LN + GEMM(Wo) + bo + resid -> out
  fused_pg<<<256, 512, 0, stream>>>(VKQ, bp, msc, lng, lnb,
                                    Wall + (size_t)1536 * 512, bo, x, out);
}

// Round 5
// 221.664 us; speedup vs baseline: 1.1086x; 1.1086x over previous
//
#include <hip/hip_runtime.h>
#include <hip/hip_bf16.h>

// ---------------------------------------------------------------------------
// OrthoInitPhasor round 5
//   prep_all:     cvt x->bf16, pack Wv/Wo, cvt Wkm/Wqm, transpose Wk/Wq,
//                 compose biases                     (one kernel)
//   gemm_compose: Wkk = Wkm@Wk, Wqq = Wqm@Wq via MFMA
//   GEMM_A:       x @ [Wv|Wkk|Wqq]^T + bias -> VKQ planar [16384,1536] bf16
//   fused_pg:     phasor+cumsum+LN (LDS) + MFMA GEMM vs Wo + resid -> out
// ---------------------------------------------------------------------------

typedef __attribute__((ext_vector_type(8))) short short8;   // 8 x bf16
typedef __attribute__((ext_vector_type(4))) float f32x4;

#define M_TOK   16384
#define DIM     512
#define NCHUNK  64
#define RPAD    520   // LDS row stride (bf16 elems) for normed tile

__device__ __forceinline__ void gll16(const void* g, void* l) {
  __builtin_amdgcn_global_load_lds(
      (const __attribute__((address_space(1))) unsigned int*)g,
      (__attribute__((address_space(3))) unsigned int*)l, 16, 0, 0);
}

__device__ __forceinline__ uint2 pack4bf(float4 v) {
  union { __hip_bfloat16 h[4]; uint2 u; } t;
  t.h[0] = __float2bfloat16(v.x);
  t.h[1] = __float2bfloat16(v.y);
  t.h[2] = __float2bfloat16(v.z);
  t.h[3] = __float2bfloat16(v.w);
  return t.u;
}

// ------------------------------ prep (merged) ------------------------------
__global__ __launch_bounds__(256) void prep_all(
    const float* __restrict__ x, __hip_bfloat16* __restrict__ x_bf,
    const float* __restrict__ Wv, const float* __restrict__ Wo,
    const float* __restrict__ bv,
    const float* __restrict__ Wkm, const float* __restrict__ Wqm,
    const float* __restrict__ Wk, const float* __restrict__ Wq,
    const float* __restrict__ bk, const float* __restrict__ bkm,
    const float* __restrict__ bq, const float* __restrict__ bqm,
    __hip_bfloat16* __restrict__ Wall, float* __restrict__ bc1,
    __hip_bfloat16* __restrict__ Wm_bf, __hip_bfloat16* __restrict__ WT_bf) {
  const int tid = threadIdx.x;
  if (blockIdx.x < 8192) {
    int i = blockIdx.x * 256 + tid;          // 2097152 float4s
    ((uint2*)x_bf)[i] = pack4bf(((const float4*)x)[i]);
    return;
  }
  const int b = blockIdx.x - 8192;
  if (b < 512) {
    int m = b >> 8;
    int idx = ((b & 255) * 256 + tid) * 4;
    const float* src = m ? Wo : Wv;
    __hip_bfloat16* dst = Wall + (m ? (size_t)1536 * 512 : 0);
    ((uint2*)dst)[idx >> 2] = pack4bf(*(const float4*)(src + idx));
    int t = b * 256 + tid;
    if (t < 512) bc1[t] = bv[t];
  } else if (b < 1024) {
    int bb = b - 512;
    int m = bb >> 8;
    int idx = ((bb & 255) * 256 + tid) * 4;
    const float* src = m ? Wqm : Wkm;
    ((uint2*)(Wm_bf + (size_t)m * 262144))[idx >> 2] =
        pack4bf(*(const float4*)(src + idx));
  } else if (b < 1152) {
    __shared__ float tile[64][65];
    int bb = b - 1024;
    int z = bb >> 6;
    int tl = bb & 63;
    int tr = tl >> 3, tc = tl & 7;
    const float* src = z ? Wq : Wk;
#pragma unroll
    for (int i = 0; i < 4; i++) {
      int r = (tid >> 4) + 16 * i;
      int c4 = (tid & 15) * 4;
      float4 v = *(const float4*)(src + (size_t)(tr * 64 + r) * 512 +
                                  tc * 64 + c4);
      tile[r][c4 + 0] = v.x;
      tile[r][c4 + 1] = v.y;
      tile[r][c4 + 2] = v.z;
      tile[r][c4 + 3] = v.w;
    }
    __syncthreads();
    int orow = tid >> 2;
    int seg = tid & 3;
    __hip_bfloat16* dst = WT_bf + (size_t)z * 262144 +
                          (size_t)(tc * 64 + orow) * 512 + tr * 64 + seg * 16;
#pragma unroll
    for (int q = 0; q < 4; q++) {
      float4 v;
      v.x = tile[seg * 16 + q * 4 + 0][orow];
      v.y = tile[seg * 16 + q * 4 + 1][orow];
      v.z = tile[seg * 16 + q * 4 + 2][orow];
      v.w = tile[seg * 16 + q * 4 + 3][orow];
      *(uint2*)(dst + q * 4) = pack4bf(v);
    }
  } else {
    int row = (b - 1152) * 4 + (tid >> 6);
    int lane = tid & 63;
    int z = row >> 9;
    int i = row & 511;
    const float* Wm = z ? Wqm : Wkm;
    const float* b0 = z ? bq : bk;
    const float* bm = z ? bqm : bkm;
    const float4* w4 = (const float4*)(Wm + (size_t)i * 512 + lane * 8);
    const float4* v4 = (const float4*)(b0 + lane * 8);
    float4 w0 = w4[0], w1 = w4[1], c0 = v4[0], c1 = v4[1];
    float acc = w0.x * c0.x + w0.y * c0.y + w0.z * c0.z + w0.w * c0.w +
                w1.x * c1.x + w1.y * c1.y + w1.z * c1.z + w1.w * c1.w;
#pragma unroll
    for (int off = 32; off; off >>= 1) acc += __shfl_xor(acc, off, 64);
    if (lane == 0) bc1[512 + z * 512 + i] = acc + bm[i];
  }
}

// ------------------------------- GEMM (B^T) --------------------------------
// C[m,n] = sum_k A[m,k] * Bt[n,k] + bias[n], bf16 planar store (ldc)
__global__ __launch_bounds__(256) void gemm_bt(
    const __hip_bfloat16* __restrict__ A, int lda,
    const __hip_bfloat16* __restrict__ Bt,
    const float* __restrict__ bias,
    __hip_bfloat16* __restrict__ Cout, int ldc) {
  constexpr int K = 512, BK = 32;
  __shared__ __align__(16) __hip_bfloat16 As[128 * BK];
  __shared__ __align__(16) __hip_bfloat16 Bs[128 * BK];

  const int tid  = threadIdx.x;
  const int lane = tid & 63;
  const int w    = tid >> 6;
  const int wm   = w >> 1;
  const int wn   = w & 1;
  const int m0   = blockIdx.y * 128;
  const int n0   = blockIdx.x * 128;

  const int rS0    = (w * 2 + 0) * 16 + (lane >> 2);
  const int rS1    = (w * 2 + 1) * 16 + (lane >> 2);
  const int kInRow = (lane & 3) * 8;
  const __hip_bfloat16* gA0 = A + (size_t)(m0 + rS0) * lda + kInRow;
  const __hip_bfloat16* gA1 = A + (size_t)(m0 + rS1) * lda + kInRow;
  const __hip_bfloat16* gB0 = Bt + (size_t)(n0 + rS0) * K + kInRow;
  const __hip_bfloat16* gB1 = Bt + (size_t)(n0 + rS1) * K + kInRow;
  char* ldsA0 = (char*)As + (w * 2 + 0) * 1024;
  char* ldsA1 = (char*)As + (w * 2 + 1) * 1024;
  char* ldsB0 = (char*)Bs + (w * 2 + 0) * 1024;
  char* ldsB1 = (char*)Bs + (w * 2 + 1) * 1024;

  f32x4 acc[4][4] = {};

  const int rfA = lane & 15;
  const int rfK = (lane >> 4) * 8;

  for (int kt = 0; kt < K; kt += BK) {
    __syncthreads();
    gll16(gA0 + kt, ldsA0);
    gll16(gA1 + kt, ldsA1);
    gll16(gB0 + kt, ldsB0);
    gll16(gB1 + kt, ldsB1);
    __syncthreads();

    short8 af[4], bf[4];
#pragma unroll
    for (int i = 0; i < 4; i++)
      af[i] = *(const short8*)(As + (wm * 64 + i * 16 + rfA) * BK + rfK);
#pragma unroll
    for (int j = 0; j < 4; j++)
      bf[j] = *(const short8*)(Bs + (wn * 64 + j * 16 + rfA) * BK + rfK);
#pragma unroll
    for (int i = 0; i < 4; i++)
#pragma unroll
      for (int j = 0; j < 4; j++)
        acc[i][j] = __builtin_amdgcn_mfma_f32_16x16x32_bf16(
            af[i], bf[j], acc[i][j], 0, 0, 0);
  }

  const int cq = lane >> 4;
#pragma unroll
  for (int i = 0; i < 4; i++) {
    int row = m0 + wm * 64 + i * 16 + cq * 4;
#pragma unroll
    for (int j = 0; j < 4; j++) {
      int col = n0 + wn * 64 + j * 16 + (lane & 15);
      float bz = bias[col];
#pragma unroll
      for (int r = 0; r < 4; r++) {
        float v = acc[i][j][r] + bz;
        Cout[(size_t)(row + r) * ldc + col] = __float2bfloat16(v);
      }
    }
  }
}

// --------------- compose GEMM: Wkk=Wkm@Wk, Wqq=Wqm@Wq (MFMA) ---------------
__global__ __launch_bounds__(256) void gemm_compose(
    const __hip_bfloat16* __restrict__ Wm_bf,
    const __hip_bfloat16* __restrict__ WT_bf,
    __hip_bfloat16* __restrict__ Wall) {
  constexpr int K = 512, BK = 32;
  const __hip_bfloat16* A  = Wm_bf + (size_t)blockIdx.z * 262144;
  const __hip_bfloat16* Bt = WT_bf + (size_t)blockIdx.z * 262144;
  __hip_bfloat16* C = Wall + (size_t)(512 + blockIdx.z * 512) * 512;
  __shared__ __align__(16) __hip_bfloat16 As[128 * BK];
  __shared__ __align__(16) __hip_bfloat16 Bs[128 * BK];

  const int tid  = threadIdx.x;
  const int lane = tid & 63;
  const int w    = tid >> 6;
  const int wm   = w >> 1;
  const int wn   = w & 1;
  const int m0   = blockIdx.y * 128;
  const int n0   = blockIdx.x * 128;

  const int rS0    = (w * 2 + 0) * 16 + (lane >> 2);
  const int rS1    = (w * 2 + 1) * 16 + (lane >> 2);
  const int kInRow = (lane & 3) * 8;
  const __hip_bfloat16* gA0 = A + (size_t)(m0 + rS0) * K + kInRow;
  const __hip_bfloat16* gA1 = A + (size_t)(m0 + rS1) * K + kInRow;
  const __hip_bfloat16* gB0 = Bt + (size_t)(n0 + rS0) * K + kInRow;
  const __hip_bfloat16* gB1 = Bt + (size_t)(n0 + rS1) * K + kInRow;
  char* ldsA0 = (char*)As + (w * 2 + 0) * 1024;
  char* ldsA1 = (char*)As + (w * 2 + 1) * 1024;
  char* ldsB0 = (char*)Bs + (w * 2 + 0) * 1024;
  char* ldsB1 = (char*)Bs + (w * 2 + 1) * 1024;

  f32x4 acc[4][4] = {};
  const int rfA = lane & 15;
  const int rfK = (lane >> 4) * 8;

  for (int kt = 0; kt < K; kt += BK) {
    __syncthreads();
    gll16(gA0 + kt, ldsA0);
    gll16(gA1 + kt, ldsA1);
    gll16(gB0 + kt, ldsB0);
    gll16(gB1 + kt, ldsB1);
    __syncthreads();

    short8 af[4], bf[4];
#pragma unroll
    for (int i = 0; i < 4; i++)
      af[i] = *(const short8*)(As + (wm * 64 + i * 16 + rfA) * BK + rfK);
#pragma unroll
    for (int j = 0; j < 4; j++)
      bf[j] = *(const short8*)(Bs + (wn * 64 + j * 16 + rfA) * BK + rfK);
#pragma unroll
    for (int i = 0; i < 4; i++)
#pragma unroll
      for (int j = 0; j < 4; j++)
        acc[i][j] = __builtin_amdgcn_mfma_f32_16x16x32_bf16(
            af[i], bf[j], acc[i][j], 0, 0, 0);
  }

  const int cq = lane >> 4;
#pragma unroll
  for (int i = 0; i < 4; i++) {
    int row = m0 + wm * 64 + i * 16 + cq * 4;
#pragma unroll
    for (int j = 0; j < 4; j++) {
      int col = n0 + wn * 64 + j * 16 + (lane & 15);
#pragma unroll
      for (int r = 0; r < 4; r++)
        C[(size_t)(row + r) * 512 + col] = __float2bfloat16(acc[i][j][r]);
    }
  }
}

// ------ fused: phasor + chunk cumsum + LayerNorm + GEMM(Wo) + resid --------
// grid 256 (= B*nC), 512 threads (8 waves). One chunk (64 tokens) per block.
__global__ __launch_bounds__(512) void fused_pg(
    const __hip_bfloat16* __restrict__ VKQ,   // [16384,1536] planar
    const float* __restrict__ bp,             // [4096,512]
    const float* __restrict__ mod_scale,
    const float* __restrict__ ln_g, const float* __restrict__ ln_b,
    const __hip_bfloat16* __restrict__ WoB,   // [512,512] bf16
    const float* __restrict__ bo,
    const float* __restrict__ x,              // resid f32
    float* __restrict__ out) {
  __shared__ __hip_bfloat16 R[64 * RPAD];     // 66.5 KB
  const int tid    = threadIdx.x;
  const int blk    = blockIdx.x;
  const int token0 = blk * 64;
  const int sg0    = (blk & (NCHUNK - 1)) * 64;
  const float msc  = mod_scale[0];
  const float inv_sqrt_d = 0.044194173824159216f;

  // ---- phase 1: phasor + cumsum (thread per column d) ----
  {
    const int d = tid;                        // 0..511
    float mr = 0.f, mi = 0.f;
    const __hip_bfloat16* vb = VKQ + (size_t)token0 * 1536 + d;
    const float* bb = bp + (size_t)sg0 * 512 + d;
#pragma unroll 4
    for (int s = 0; s < 64; ++s) {
      float v  = __bfloat162float(vb[(size_t)s * 1536]);
      float km = __bfloat162float(vb[(size_t)s * 1536 + 512]);
      float qm = __bfloat162float(vb[(size_t)s * 1536 + 1024]);
      float b  = bb[(size_t)s * 512];
      float kp = b + km * msc;
      float qp = b + qm * msc;
      float sk, ck, sq, cq;
      __sincosf(kp, &sk, &ck);
      __sincosf(qp, &sq, &cq);
      mr += v * ck;
      mi += v * sk;
      R[s * RPAD + d] = __float2bfloat16((mr * cq + mi * sq) * inv_sqrt_d);
    }
  }
  __syncthreads();

  // ---- phase 1.5: LayerNorm in place (wave wv owns rows wv*8..+7) ----
  {
    const int lane = tid & 63;
    const int wv   = tid >> 6;
    float gj[8], bj[8];
#pragma unroll
    for (int j = 0; j < 8; j++) {
      int col = lane + 64 * j;
      gj[j] = ln_g[col];
      bj[j] = ln_b[col];
    }
    for (int rr = 0; rr < 8; ++rr) {
      int row = wv * 8 + rr;
      float vals[8], sum = 0.f, sq2 = 0.f;
#pragma unroll
      for (int j = 0; j < 8; j++) {
        float v = __bfloat162float(R[row * RPAD + lane + 64 * j]);
        vals[j] = v;
        sum += v;
        sq2 += v * v;
      }
#pragma unroll
      for (int off = 32; off; off >>= 1) {
        sum += __shfl_xor(sum, off, 64);
        sq2 += __shfl_xor(sq2, off, 64);
      }
      float mu   = sum * (1.f / 512.f);
      float var  = sq2 * (1.f / 512.f) - mu * mu;
      float rstd = rsqrtf(var + 1e-5f);
#pragma unroll
      for (int j = 0; j < 8; j++) {
        float nv = (vals[j] - mu) * rstd * gj[j] + bj[j];
        R[row * RPAD + lane + 64 * j] = __float2bfloat16(nv);
      }
    }
  }
  __syncthreads();

  // ---- phase 2: C(64x512) = R(64x512) @ WoB^T + bo + x -> out ----
  {
    const int lane = tid & 63;
    const int w    = tid >> 6;                // wave 0..7 -> cols w*64..+63
    const int rfA  = lane & 15;
    const int rfK  = (lane >> 4) * 8;
    f32x4 acc[4][4] = {};

    for (int kt = 0; kt < 512; kt += 32) {
      short8 af[4], bf[4];
#pragma unroll
      for (int j = 0; j < 4; j++) {
        int col = w * 64 + j * 16 + rfA;
        bf[j] = *(const short8*)(WoB + (size_t)col * 512 + kt + rfK);
      }
#pragma unroll
      for (int i = 0; i < 4; i++)
        af[i] = *(const short8*)(R + (i * 16 + rfA) * RPAD + kt + rfK);
#pragma unroll
      for (int i = 0; i < 4; i++)
#pragma unroll
        for (int j = 0; j < 4; j++)
          acc[i][j] = __builtin_amdgcn_mfma_f32_16x16x32_bf16(
              af[i], bf[j], acc[i][j], 0, 0, 0);
    }

    const int cq = lane >> 4;
    float bz[4];
#pragma unroll
    for (int j = 0; j < 4; j++) bz[j] = bo[w * 64 + j * 16 + (lane & 15)];
#pragma unroll
    for (int i = 0; i < 4; i++) {
      int row = token0 + i * 16 + cq * 4;
#pragma unroll
      for (int j = 0; j < 4; j++) {
        int col = w * 64 + j * 16 + (lane & 15);
#pragma unroll
        for (int r = 0; r < 4; r++) {
          size_t o = (size_t)(row + r) * 512 + col;
          out[o] = acc[i][j][r] + bz[j] + x[o];
        }
      }
    }
  }
}

// ------------------------------- launcher ----------------------------------
extern "C" void kernel_launch(void* const* d_in, const int* in_sizes, int n_in,
                              void* d_out, int out_size, void* d_ws,
                              size_t ws_size, hipStream_t stream) {
  const float* x    = (const float*)d_in[0];
  const float* bp   = (const float*)d_in[1];
  const float* Wk   = (const float*)d_in[2];
  const float* bk   = (const float*)d_in[3];
  const float* Wv   = (const float*)d_in[4];
  const float* bv   = (const float*)d_in[5];
  const float* Wq   = (const float*)d_in[6];
  const float* bq   = (const float*)d_in[7];
  const float* Wkm  = (const float*)d_in[8];
  const float* bkm  = (const float*)d_in[9];
  const float* Wqm  = (const float*)d_in[10];
  const float* bqm  = (const float*)d_in[11];
  const float* msc  = (const float*)d_in[12];
  const float* lng  = (const float*)d_in[13];
  const float* lnb  = (const float*)d_in[14];
  const float* Wo   = (const float*)d_in[15];
  const float* bo   = (const float*)d_in[16];
  float* out = (float*)d_out;

  char* ws = (char*)d_ws;
  __hip_bfloat16* x_bf  = (__hip_bfloat16*)ws;  ws += (size_t)M_TOK * DIM * 2;
  __hip_bfloat16* Wall  = (__hip_bfloat16*)ws;  ws += (size_t)2048 * 512 * 2;
  __hip_bfloat16* Wm_bf = (__hip_bfloat16*)ws;  ws += (size_t)2 * 262144 * 2;
  __hip_bfloat16* WT_bf = (__hip_bfloat16*)ws;  ws += (size_t)2 * 262144 * 2;
  float*          bc1   = (float*)ws;           ws += 1536 * 4;
  __hip_bfloat16* VKQ   = (__hip_bfloat16*)ws;  ws += (size_t)M_TOK * 1536 * 2;

  // 1) merged prep: cvt x + pack/cvt/transpose weights + compose biases
  prep_all<<<9600, 256, 0, stream>>>(x, x_bf, Wv, Wo, bv, Wkm, Wqm, Wk, Wq,
                                     bk, bkm, bq, bqm, Wall, bc1, Wm_bf,
                                     WT_bf);
  // 2) MFMA compose: Wkk, Wqq -> Wall rows 512..1535
  gemm_compose<<<dim3(4, 4, 2), 256, 0, stream>>>(Wm_bf, WT_bf, Wall);
  // 3) VKQ = x @ [Wv|Wkk|Wqq]^T + bias, planar [16384,1536]
  gemm_bt<<<dim3(12, 128), 256, 0, stream>>>(x_bf, DIM, Wall, bc1, VKQ, 1536);
  // 4) fused phasor + cumsum + LN + GEMM(Wo) + bo + resid -> out
  fused_pg<<<256, 512, 0, stream>>>(VKQ, bp, msc, lng, lnb,
                                    Wall + (size_t)1536 * 512, bo, x, out);
}

// Round 6
// 203.659 us; speedup vs baseline: 1.2066x; 1.0884x over previous
//
#include <hip/hip_runtime.h>
#include <hip/hip_bf16.h>

// ---------------------------------------------------------------------------
// OrthoInitPhasor round 6
//   prep_all:     cvt x->bf16, pack Wv/Wo, cvt Wkm/Wqm, transpose Wk/Wq,
//                 compose biases
//   gemm_compose: Wkk = Wkm@Wk, Wqq = Wqm@Wq via MFMA
//   GEMM_A:       x @ [Wv|Wkk|Wqq]^T + bias -> VKQ planar [16384,1536] bf16
//   fused_pg:     1024-thread, 2-segment split-scan phasor+cumsum+LN
//                 + MFMA GEMM vs Wo + resid -> out
// ---------------------------------------------------------------------------

typedef __attribute__((ext_vector_type(8))) short short8;   // 8 x bf16
typedef __attribute__((ext_vector_type(4))) float f32x4;

#define M_TOK   16384
#define DIM     512
#define NCHUNK  64
#define RPAD    520   // LDS row stride (bf16 elems) for normed tile

__device__ __forceinline__ void gll16(const void* g, void* l) {
  __builtin_amdgcn_global_load_lds(
      (const __attribute__((address_space(1))) unsigned int*)g,
      (__attribute__((address_space(3))) unsigned int*)l, 16, 0, 0);
}

__device__ __forceinline__ uint2 pack4bf(float4 v) {
  union { __hip_bfloat16 h[4]; uint2 u; } t;
  t.h[0] = __float2bfloat16(v.x);
  t.h[1] = __float2bfloat16(v.y);
  t.h[2] = __float2bfloat16(v.z);
  t.h[3] = __float2bfloat16(v.w);
  return t.u;
}

// ------------------------------ prep (merged) ------------------------------
__global__ __launch_bounds__(256) void prep_all(
    const float* __restrict__ x, __hip_bfloat16* __restrict__ x_bf,
    const float* __restrict__ Wv, const float* __restrict__ Wo,
    const float* __restrict__ bv,
    const float* __restrict__ Wkm, const float* __restrict__ Wqm,
    const float* __restrict__ Wk, const float* __restrict__ Wq,
    const float* __restrict__ bk, const float* __restrict__ bkm,
    const float* __restrict__ bq, const float* __restrict__ bqm,
    __hip_bfloat16* __restrict__ Wall, float* __restrict__ bc1,
    __hip_bfloat16* __restrict__ Wm_bf, __hip_bfloat16* __restrict__ WT_bf) {
  const int tid = threadIdx.x;
  if (blockIdx.x < 8192) {
    int i = blockIdx.x * 256 + tid;          // 2097152 float4s
    ((uint2*)x_bf)[i] = pack4bf(((const float4*)x)[i]);
    return;
  }
  const int b = blockIdx.x - 8192;
  if (b < 512) {
    int m = b >> 8;
    int idx = ((b & 255) * 256 + tid) * 4;
    const float* src = m ? Wo : Wv;
    __hip_bfloat16* dst = Wall + (m ? (size_t)1536 * 512 : 0);
    ((uint2*)dst)[idx >> 2] = pack4bf(*(const float4*)(src + idx));
    int t = b * 256 + tid;
    if (t < 512) bc1[t] = bv[t];
  } else if (b < 1024) {
    int bb = b - 512;
    int m = bb >> 8;
    int idx = ((bb & 255) * 256 + tid) * 4;
    const float* src = m ? Wqm : Wkm;
    ((uint2*)(Wm_bf + (size_t)m * 262144))[idx >> 2] =
        pack4bf(*(const float4*)(src + idx));
  } else if (b < 1152) {
    __shared__ float tile[64][65];
    int bb = b - 1024;
    int z = bb >> 6;
    int tl = bb & 63;
    int tr = tl >> 3, tc = tl & 7;
    const float* src = z ? Wq : Wk;
#pragma unroll
    for (int i = 0; i < 4; i++) {
      int r = (tid >> 4) + 16 * i;
      int c4 = (tid & 15) * 4;
      float4 v = *(const float4*)(src + (size_t)(tr * 64 + r) * 512 +
                                  tc * 64 + c4);
      tile[r][c4 + 0] = v.x;
      tile[r][c4 + 1] = v.y;
      tile[r][c4 + 2] = v.z;
      tile[r][c4 + 3] = v.w;
    }
    __syncthreads();
    int orow = tid >> 2;
    int seg = tid & 3;
    __hip_bfloat16* dst = WT_bf + (size_t)z * 262144 +
                          (size_t)(tc * 64 + orow) * 512 + tr * 64 + seg * 16;
#pragma unroll
    for (int q = 0; q < 4; q++) {
      float4 v;
      v.x = tile[seg * 16 + q * 4 + 0][orow];
      v.y = tile[seg * 16 + q * 4 + 1][orow];
      v.z = tile[seg * 16 + q * 4 + 2][orow];
      v.w = tile[seg * 16 + q * 4 + 3][orow];
      *(uint2*)(dst + q * 4) = pack4bf(v);
    }
  } else {
    int row = (b - 1152) * 4 + (tid >> 6);
    int lane = tid & 63;
    int z = row >> 9;
    int i = row & 511;
    const float* Wm = z ? Wqm : Wkm;
    const float* b0 = z ? bq : bk;
    const float* bm = z ? bqm : bkm;
    const float4* w4 = (const float4*)(Wm + (size_t)i * 512 + lane * 8);
    const float4* v4 = (const float4*)(b0 + lane * 8);
    float4 w0 = w4[0], w1 = w4[1], c0 = v4[0], c1 = v4[1];
    float acc = w0.x * c0.x + w0.y * c0.y + w0.z * c0.z + w0.w * c0.w +
                w1.x * c1.x + w1.y * c1.y + w1.z * c1.z + w1.w * c1.w;
#pragma unroll
    for (int off = 32; off; off >>= 1) acc += __shfl_xor(acc, off, 64);
    if (lane == 0) bc1[512 + z * 512 + i] = acc + bm[i];
  }
}

// ------------------------------- GEMM (B^T) --------------------------------
// C[m,n] = sum_k A[m,k] * Bt[n,k] + bias[n], bf16 planar store (ldc)
__global__ __launch_bounds__(256) void gemm_bt(
    const __hip_bfloat16* __restrict__ A, int lda,
    const __hip_bfloat16* __restrict__ Bt,
    const float* __restrict__ bias,
    __hip_bfloat16* __restrict__ Cout, int ldc) {
  constexpr int K = 512, BK = 32;
  __shared__ __align__(16) __hip_bfloat16 As[128 * BK];
  __shared__ __align__(16) __hip_bfloat16 Bs[128 * BK];

  const int tid  = threadIdx.x;
  const int lane = tid & 63;
  const int w    = tid >> 6;
  const int wm   = w >> 1;
  const int wn   = w & 1;
  const int m0   = blockIdx.y * 128;
  const int n0   = blockIdx.x * 128;

  const int rS0    = (w * 2 + 0) * 16 + (lane >> 2);
  const int rS1    = (w * 2 + 1) * 16 + (lane >> 2);
  const int kInRow = (lane & 3) * 8;
  const __hip_bfloat16* gA0 = A + (size_t)(m0 + rS0) * lda + kInRow;
  const __hip_bfloat16* gA1 = A + (size_t)(m0 + rS1) * lda + kInRow;
  const __hip_bfloat16* gB0 = Bt + (size_t)(n0 + rS0) * K + kInRow;
  const __hip_bfloat16* gB1 = Bt + (size_t)(n0 + rS1) * K + kInRow;
  char* ldsA0 = (char*)As + (w * 2 + 0) * 1024;
  char* ldsA1 = (char*)As + (w * 2 + 1) * 1024;
  char* ldsB0 = (char*)Bs + (w * 2 + 0) * 1024;
  char* ldsB1 = (char*)Bs + (w * 2 + 1) * 1024;

  f32x4 acc[4][4] = {};

  const int rfA = lane & 15;
  const int rfK = (lane >> 4) * 8;

  for (int kt = 0; kt < K; kt += BK) {
    __syncthreads();
    gll16(gA0 + kt, ldsA0);
    gll16(gA1 + kt, ldsA1);
    gll16(gB0 + kt, ldsB0);
    gll16(gB1 + kt, ldsB1);
    __syncthreads();

    short8 af[4], bf[4];
#pragma unroll
    for (int i = 0; i < 4; i++)
      af[i] = *(const short8*)(As + (wm * 64 + i * 16 + rfA) * BK + rfK);
#pragma unroll
    for (int j = 0; j < 4; j++)
      bf[j] = *(const short8*)(Bs + (wn * 64 + j * 16 + rfA) * BK + rfK);
#pragma unroll
    for (int i = 0; i < 4; i++)
#pragma unroll
      for (int j = 0; j < 4; j++)
        acc[i][j] = __builtin_amdgcn_mfma_f32_16x16x32_bf16(
            af[i], bf[j], acc[i][j], 0, 0, 0);
  }

  const int cq = lane >> 4;
#pragma unroll
  for (int i = 0; i < 4; i++) {
    int row = m0 + wm * 64 + i * 16 + cq * 4;
#pragma unroll
    for (int j = 0; j < 4; j++) {
      int col = n0 + wn * 64 + j * 16 + (lane & 15);
      float bz = bias[col];
#pragma unroll
      for (int r = 0; r < 4; r++) {
        float v = acc[i][j][r] + bz;
        Cout[(size_t)(row + r) * ldc + col] = __float2bfloat16(v);
      }
    }
  }
}

// --------------- compose GEMM: Wkk=Wkm@Wk, Wqq=Wqm@Wq (MFMA) ---------------
__global__ __launch_bounds__(256) void gemm_compose(
    const __hip_bfloat16* __restrict__ Wm_bf,
    const __hip_bfloat16* __restrict__ WT_bf,
    __hip_bfloat16* __restrict__ Wall) {
  constexpr int K = 512, BK = 32;
  const __hip_bfloat16* A  = Wm_bf + (size_t)blockIdx.z * 262144;
  const __hip_bfloat16* Bt = WT_bf + (size_t)blockIdx.z * 262144;
  __hip_bfloat16* C = Wall + (size_t)(512 + blockIdx.z * 512) * 512;
  __shared__ __align__(16) __hip_bfloat16 As[128 * BK];
  __shared__ __align__(16) __hip_bfloat16 Bs[128 * BK];

  const int tid  = threadIdx.x;
  const int lane = tid & 63;
  const int w    = tid >> 6;
  const int wm   = w >> 1;
  const int wn   = w & 1;
  const int m0   = blockIdx.y * 128;
  const int n0   = blockIdx.x * 128;

  const int rS0    = (w * 2 + 0) * 16 + (lane >> 2);
  const int rS1    = (w * 2 + 1) * 16 + (lane >> 2);
  const int kInRow = (lane & 3) * 8;
  const __hip_bfloat16* gA0 = A + (size_t)(m0 + rS0) * K + kInRow;
  const __hip_bfloat16* gA1 = A + (size_t)(m0 + rS1) * K + kInRow;
  const __hip_bfloat16* gB0 = Bt + (size_t)(n0 + rS0) * K + kInRow;
  const __hip_bfloat16* gB1 = Bt + (size_t)(n0 + rS1) * K + kInRow;
  char* ldsA0 = (char*)As + (w * 2 + 0) * 1024;
  char* ldsA1 = (char*)As + (w * 2 + 1) * 1024;
  char* ldsB0 = (char*)Bs + (w * 2 + 0) * 1024;
  char* ldsB1 = (char*)Bs + (w * 2 + 1) * 1024;

  f32x4 acc[4][4] = {};
  const int rfA = lane & 15;
  const int rfK = (lane >> 4) * 8;

  for (int kt = 0; kt < K; kt += BK) {
    __syncthreads();
    gll16(gA0 + kt, ldsA0);
    gll16(gA1 + kt, ldsA1);
    gll16(gB0 + kt, ldsB0);
    gll16(gB1 + kt, ldsB1);
    __syncthreads();

    short8 af[4], bf[4];
#pragma unroll
    for (int i = 0; i < 4; i++)
      af[i] = *(const short8*)(As + (wm * 64 + i * 16 + rfA) * BK + rfK);
#pragma unroll
    for (int j = 0; j < 4; j++)
      bf[j] = *(const short8*)(Bs + (wn * 64 + j * 16 + rfA) * BK + rfK);
#pragma unroll
    for (int i = 0; i < 4; i++)
#pragma unroll
      for (int j = 0; j < 4; j++)
        acc[i][j] = __builtin_amdgcn_mfma_f32_16x16x32_bf16(
            af[i], bf[j], acc[i][j], 0, 0, 0);
  }

  const int cq = lane >> 4;
#pragma unroll
  for (int i = 0; i < 4; i++) {
    int row = m0 + wm * 64 + i * 16 + cq * 4;
#pragma unroll
    for (int j = 0; j < 4; j++) {
      int col = n0 + wn * 64 + j * 16 + (lane & 15);
#pragma unroll
      for (int r = 0; r < 4; r++)
        C[(size_t)(row + r) * 512 + col] = __float2bfloat16(acc[i][j][r]);
    }
  }
}

// ------ fused: phasor + split-scan cumsum + LN + GEMM(Wo) + resid ----------
// grid 256 (= B*nC), 1024 threads (16 waves). One chunk (64 tokens) / block.
// Phase 1a: thread (seg=tid>>9, d=tid&511) does 32-token local phasor-cumsum,
//           writes partial retrieved to R; seg0 totals -> Tr/Ti (LDS).
// Phase 1b: all threads fix rows 32..63: R += prefix·(cos,sin)(qp),
//           qp recomputed from L2-warm qm/bp reloads.
// Phase 2:  LN (4 rows/wave) then MFMA GEMM vs Wo (32 cols/wave) + bo + x.
__global__ __launch_bounds__(1024) void fused_pg(
    const __hip_bfloat16* __restrict__ VKQ,   // [16384,1536] planar
    const float* __restrict__ bp,             // [4096,512]
    const float* __restrict__ mod_scale,
    const float* __restrict__ ln_g, const float* __restrict__ ln_b,
    const __hip_bfloat16* __restrict__ WoB,   // [512,512] bf16
    const float* __restrict__ bo,
    const float* __restrict__ x,              // resid f32
    float* __restrict__ out) {
  __shared__ __hip_bfloat16 R[64 * RPAD];     // 66.5 KB
  __shared__ float Tr[512], Ti[512];          // seg0 complex totals
  const int tid    = threadIdx.x;
  const int seg    = tid >> 9;                // 0 or 1
  const int d      = tid & 511;
  const int blk    = blockIdx.x;
  const int token0 = blk * 64;
  const int sg0    = (blk & (NCHUNK - 1)) * 64;
  const float msc  = mod_scale[0];
  const float isd  = 0.044194173824159216f;   // 1/sqrt(512)

  // ---- phase 1a: per-segment local phasor + cumsum (32 tokens) ----
  {
    const int s0 = seg * 32;
    float mr = 0.f, mi = 0.f;
    const __hip_bfloat16* vb = VKQ + (size_t)(token0 + s0) * 1536 + d;
    const float* bb = bp + (size_t)(sg0 + s0) * 512 + d;
#pragma unroll 4
    for (int s = 0; s < 32; ++s) {
      float v  = __bfloat162float(vb[(size_t)s * 1536]);
      float km = __bfloat162float(vb[(size_t)s * 1536 + 512]);
      float qm = __bfloat162float(vb[(size_t)s * 1536 + 1024]);
      float b  = bb[(size_t)s * 512];
      float kp = b + km * msc;
      float qp = b + qm * msc;
      float sk, ck, sq, cq;
      __sincosf(kp, &sk, &ck);
      __sincosf(qp, &sq, &cq);
      mr += v * ck;
      mi += v * sk;
      R[(s0 + s) * RPAD + d] = __float2bfloat16((mr * cq + mi * sq) * isd);
    }
    if (seg == 0) {
      Tr[d] = mr;
      Ti[d] = mi;
    }
  }
  __syncthreads();

  // ---- phase 1b: fixup rows 32..63 with seg0 prefix (all 1024 threads) ----
  {
    const int r0 = 32 + seg * 16;             // 16 rows per thread-half
    const float pr = Tr[d] * isd;
    const float pi = Ti[d] * isd;
    const __hip_bfloat16* qb = VKQ + (size_t)(token0 + r0) * 1536 + 1024 + d;
    const float* bb = bp + (size_t)(sg0 + r0) * 512 + d;
#pragma unroll 4
    for (int s = 0; s < 16; ++s) {
      float qm = __bfloat162float(qb[(size_t)s * 1536]);
      float b  = bb[(size_t)s * 512];
      float qp = b + qm * msc;
      float sq, cq;
      __sincosf(qp, &sq, &cq);
      int idx = (r0 + s) * RPAD + d;
      float v = __bfloat162float(R[idx]) + pr * cq + pi * sq;
      R[idx] = __float2bfloat16(v);
    }
  }
  __syncthreads();

  // ---- LayerNorm in place (wave wv owns rows wv*4..+3) ----
  {
    const int lane = tid & 63;
    const int wv   = tid >> 6;                // 0..15
    float gj[8], bj[8];
#pragma unroll
    for (int j = 0; j < 8; j++) {
      int col = lane + 64 * j;
      gj[j] = ln_g[col];
      bj[j] = ln_b[col];
    }
    for (int rr = 0; rr < 4; ++rr) {
      int row = wv * 4 + rr;
      float vals[8], sum = 0.f, sq2 = 0.f;
#pragma unroll
      for (int j = 0; j < 8; j++) {
        float v = __bfloat162float(R[row * RPAD + lane + 64 * j]);
        vals[j] = v;
        sum += v;
        sq2 += v * v;
      }
#pragma unroll
      for (int off = 32; off; off >>= 1) {
        sum += __shfl_xor(sum, off, 64);
        sq2 += __shfl_xor(sq2, off, 64);
      }
      float mu   = sum * (1.f / 512.f);
      float var  = sq2 * (1.f / 512.f) - mu * mu;
      float rstd = rsqrtf(var + 1e-5f);
#pragma unroll
      for (int j = 0; j < 8; j++) {
        float nv = (vals[j] - mu) * rstd * gj[j] + bj[j];
        R[row * RPAD + lane + 64 * j] = __float2bfloat16(nv);
      }
    }
  }
  __syncthreads();

  // ---- phase 2: C(64x512) = R @ WoB^T + bo + x -> out (16 waves) ----
  {
    const int lane = tid & 63;
    const int w    = tid >> 6;                // wave 0..15 -> cols w*32..+31
    const int rfA  = lane & 15;
    const int rfK  = (lane >> 4) * 8;
    f32x4 acc[4][2] = {};

    for (int kt = 0; kt < 512; kt += 32) {
      short8 af[4], bf[2];
#pragma unroll
      for (int j = 0; j < 2; j++) {
        int col = w * 32 + j * 16 + rfA;
        bf[j] = *(const short8*)(WoB + (size_t)col * 512 + kt + rfK);
      }
#pragma unroll
      for (int i = 0; i < 4; i++)
        af[i] = *(const short8*)(R + (i * 16 + rfA) * RPAD + kt + rfK);
#pragma unroll
      for (int i = 0; i < 4; i++)
#pragma unroll
        for (int j = 0; j < 2; j++)
          acc[i][j] = __builtin_amdgcn_mfma_f32_16x16x32_bf16(
              af[i], bf[j], acc[i][j], 0, 0, 0);
    }

    const int cq = lane >> 4;
    float bz[2];
#pragma unroll
    for (int j = 0; j < 2; j++) bz[j] = bo[w * 32 + j * 16 + (lane & 15)];
#pragma unroll
    for (int i = 0; i < 4; i++) {
      int row = token0 + i * 16 + cq * 4;
#pragma unroll
      for (int j = 0; j < 2; j++) {
        int col = w * 32 + j * 16 + (lane & 15);
#pragma unroll
        for (int r = 0; r < 4; r++) {
          size_t o = (size_t)(row + r) * 512 + col;
          out[o] = acc[i][j][r] + bz[j] + x[o];
        }
      }
    }
  }
}

// ------------------------------- launcher ----------------------------------
extern "C" void kernel_launch(void* const* d_in, const int* in_sizes, int n_in,
                              void* d_out, int out_size, void* d_ws,
                              size_t ws_size, hipStream_t stream) {
  const float* x    = (const float*)d_in[0];
  const float* bp   = (const float*)d_in[1];
  const float* Wk   = (const float*)d_in[2];
  const float* bk   = (const float*)d_in[3];
  const float* Wv   = (const float*)d_in[4];
  const float* bv   = (const float*)d_in[5];
  const float* Wq   = (const float*)d_in[6];
  const float* bq   = (const float*)d_in[7];
  const float* Wkm  = (const float*)d_in[8];
  const float* bkm  = (const float*)d_in[9];
  const float* Wqm  = (const float*)d_in[10];
  const float* bqm  = (const float*)d_in[11];
  const float* msc  = (const float*)d_in[12];
  const float* lng  = (const float*)d_in[13];
  const float* lnb  = (const float*)d_in[14];
  const float* Wo   = (const float*)d_in[15];
  const float* bo   = (const float*)d_in[16];
  float* out = (float*)d_out;

  char* ws = (char*)d_ws;
  __hip_bfloat16* x_bf  = (__hip_bfloat16*)ws;  ws += (size_t)M_TOK * DIM * 2;
  __hip_bfloat16* Wall  = (__hip_bfloat16*)ws;  ws += (size_t)2048 * 512 * 2;
  __hip_bfloat16* Wm_bf = (__hip_bfloat16*)ws;  ws += (size_t)2 * 262144 * 2;
  __hip_bfloat16* WT_bf = (__hip_bfloat16*)ws;  ws += (size_t)2 * 262144 * 2;
  float*          bc1   = (float*)ws;           ws += 1536 * 4;
  __hip_bfloat16* VKQ   = (__hip_bfloat16*)ws;  ws += (size_t)M_TOK * 1536 * 2;

  // 1) merged prep: cvt x + pack/cvt/transpose weights + compose biases
  prep_all<<<9600, 256, 0, stream>>>(x, x_bf, Wv, Wo, bv, Wkm, Wqm, Wk, Wq,
                                     bk, bkm, bq, bqm, Wall, bc1, Wm_bf,
                                     WT_bf);
  // 2) MFMA compose: Wkk, Wqq -> Wall rows 512..1535
  gemm_compose<<<dim3(4, 4, 2), 256, 0, stream>>>(Wm_bf, WT_bf, Wall);
  // 3) VKQ = x @ [Wv|Wkk|Wqq]^T + bias, planar [16384,1536]
  gemm_bt<<<dim3(12, 128), 256, 0, stream>>>(x_bf, DIM, Wall, bc1, VKQ, 1536);
  // 4) fused phasor + split-scan cumsum + LN + GEMM(Wo) + bo + resid -> out
  fused_pg<<<256, 1024, 0, stream>>>(VKQ, bp, msc, lng, lnb,
                                     Wall + (size_t)1536 * 512, bo, x, out);
}